// Round 8
// baseline (149.768 us; speedup 1.0000x reference)
//
#include <hip/hip_runtime.h>
#include <cstdint>
#include <cstddef>

typedef __bf16 bf16x8 __attribute__((ext_vector_type(8)));
typedef float f32x4 __attribute__((ext_vector_type(4)));

#define B_ 8
#define T_ 2048
#define C_ 1024
#define H_ 128

// C^-0.5 * log2(e): folded into Q at projection; softmax runs in exp2-space.
#define QSC 0.045084220027780106f

__device__ __forceinline__ unsigned short f2bf(float f) {
    __bf16 h = (__bf16)f;
    return *(unsigned short*)&h;
}
__device__ __forceinline__ float bf2f(unsigned short u) {
    union { unsigned int i; float f; } x; x.i = ((unsigned int)u) << 16;
    return x.f;
}

// async global->LDS, 16B per lane. LDS dest must be the wave-uniform base;
// HW adds lane*16. Global src is per-lane.
__device__ __forceinline__ void gload16(void* lds, const void* g) {
    __builtin_amdgcn_global_load_lds(
        (const __attribute__((address_space(1))) unsigned int*)g,
        (__attribute__((address_space(3))) unsigned int*)lds, 16, 0, 0);
}

// ---------------------------------------------------------------------------
// prep_w: WT[which][n][k] bf16  <-  W[k][n] f32.
// ---------------------------------------------------------------------------
__global__ __launch_bounds__(256) void prep_w(
    const float* __restrict__ Wq, const float* __restrict__ Wk,
    const float* __restrict__ Wv, unsigned short* __restrict__ wt)
{
    int gid = blockIdx.x * 256 + threadIdx.x;        // 49152 total
    int which = gid >> 14;
    int rem = gid & 16383;
    int n = rem >> 7;            // 0..127
    int kc = rem & 127;          // k-chunk of 8
    const float* W = which == 0 ? Wq : (which == 1 ? Wk : Wv);
    unsigned short tmp[8];
    #pragma unroll
    for (int i = 0; i < 8; ++i) tmp[i] = f2bf(W[(size_t)(kc * 8 + i) * H_ + n]);
    *(uint4*)&wt[((size_t)which * H_ + n) * C_ + kc * 8] = *(uint4*)tmp;
}

// ---------------------------------------------------------------------------
// proj: out = x @ W + b. x staged as F32 via gload16 (fire-and-forget, no
// VGPR roundtrip); converted to bf16 at fragment-load time (VALU, off the
// memory critical path). BM=64, BN=128, BK=64, 4 waves, double-buffered.
// LDS: x f32 32KB + W^T bf16 32KB = 64KB -> 2 blocks/CU.
// Q pre-scaled by QSC; V stored transposed [B,H,T].
// ---------------------------------------------------------------------------
__global__ __launch_bounds__(256) void proj_kernel(
    const float* __restrict__ x, const unsigned short* __restrict__ wt,
    const float* __restrict__ bq, const float* __restrict__ bk,
    const float* __restrict__ bv,
    unsigned short* __restrict__ qo, unsigned short* __restrict__ ko,
    unsigned short* __restrict__ vo)
{
    const int which = blockIdx.y;
    const float* bias = which == 0 ? bq : (which == 1 ? bk : bv);

    __shared__ float xs[2][64 * 64];             // [m][k] f32, unit-XOR swizzled
    __shared__ unsigned short ws2[2][128 * 64];  // [n][k] bf16, chunk-XOR swizzled

    const int tid = threadIdx.x;
    const int w = tid >> 6, l = tid & 63, g = l >> 4, lc = l & 15;
    const int wm = w & 1, wn = w >> 1;
    const int m0 = blockIdx.x * 64;

    const unsigned short* wbase = &wt[(size_t)which * H_ * C_];

    f32x4 acc[2][4];
    #pragma unroll
    for (int im = 0; im < 2; ++im)
        #pragma unroll
        for (int jn = 0; jn < 4; ++jn) acc[im][jn] = f32x4{0.f, 0.f, 0.f, 0.f};

    // stage one K-chunk: W (1024 16B units) + x f32 (1024 16B units)
    auto stage = [&](int buf, int kc2) {
        const int kb = kc2 * 64;
        #pragma unroll
        for (int jj = 0; jj < 4; ++jj) {
            int slot = w * 256 + jj * 64 + l;
            int r = slot >> 3, cs = slot & 7;
            gload16(&ws2[buf][(w * 256 + jj * 64) * 8],
                    &wbase[(size_t)r * C_ + kb + ((cs ^ (r & 7)) * 8)]);
        }
        #pragma unroll
        for (int jj = 0; jj < 4; ++jj) {
            int slot = w * 256 + jj * 64 + l;
            int r = slot >> 4, cs = slot & 15;
            gload16(&xs[buf][(w * 256 + jj * 64) * 4],
                    &x[(size_t)(m0 + r) * C_ + kb + ((cs ^ (r & 15)) * 4)]);
        }
    };

    stage(0, 0);
    __syncthreads();

    int cur = 0;
    for (int kc = 0; kc < 16; ++kc) {
        if (kc < 15) stage(cur ^ 1, kc + 1);
        #pragma unroll
        for (int ks = 0; ks < 2; ++ks) {
            bf16x8 a[2], b[4];
            #pragma unroll
            for (int im = 0; im < 2; ++im) {
                int row = wm * 32 + im * 16 + lc;
                int u0 = ks * 8 + g * 2;
                f32x4 lo = *(const f32x4*)&xs[cur][(row * 16 + (u0 ^ (row & 15))) * 4];
                f32x4 hi = *(const f32x4*)&xs[cur][(row * 16 + ((u0 + 1) ^ (row & 15))) * 4];
                bf16x8 af;
                af[0] = (__bf16)lo[0]; af[1] = (__bf16)lo[1];
                af[2] = (__bf16)lo[2]; af[3] = (__bf16)lo[3];
                af[4] = (__bf16)hi[0]; af[5] = (__bf16)hi[1];
                af[6] = (__bf16)hi[2]; af[7] = (__bf16)hi[3];
                a[im] = af;
            }
            #pragma unroll
            for (int jn = 0; jn < 4; ++jn) {
                int n = wn * 64 + jn * 16 + lc;
                b[jn] = *(const bf16x8*)&ws2[cur][(n * 8 + ((ks * 4 + g) ^ (n & 7))) * 8];
            }
            #pragma unroll
            for (int im = 0; im < 2; ++im)
                #pragma unroll
                for (int jn = 0; jn < 4; ++jn)
                    acc[im][jn] = __builtin_amdgcn_mfma_f32_16x16x32_bf16(
                        a[im], b[jn], acc[im][jn], 0, 0, 0);
        }
        __syncthreads();
        cur ^= 1;
    }

    // epilogue: bias + repack through LDS (reuse xs[0] as ushort [64][128])
    unsigned short* eb = (unsigned short*)&xs[0][0];
    if (which != 2) {
        const float osc = (which == 0) ? QSC : 1.0f;
        #pragma unroll
        for (int jn = 0; jn < 4; ++jn) {
            int n = wn * 64 + jn * 16 + lc;
            float bval = bias[n];
            #pragma unroll
            for (int im = 0; im < 2; ++im)
                #pragma unroll
                for (int r = 0; r < 4; ++r) {
                    int ml = wm * 32 + im * 16 + g * 4 + r;
                    eb[ml * 128 + n] = f2bf((acc[im][jn][r] + bval) * osc);
                }
        }
        __syncthreads();
        unsigned short* o = which == 0 ? qo : ko;
        #pragma unroll
        for (int i = 0; i < 4; ++i) {
            int cidx = i * 256 + tid;
            int row = cidx >> 4, c16 = cidx & 15;
            *(uint4*)&o[(size_t)(m0 + row) * H_ + c16 * 8] =
                *(const uint4*)&eb[row * 128 + c16 * 8];
        }
    } else {
        #pragma unroll
        for (int jn = 0; jn < 4; ++jn) {
            int n = wn * 64 + jn * 16 + lc;
            float bval = bias[n];
            #pragma unroll
            for (int im = 0; im < 2; ++im)
                #pragma unroll
                for (int r = 0; r < 4; ++r) {
                    int ml = wm * 32 + im * 16 + g * 4 + r;
                    eb[n * 64 + ml] = f2bf(acc[im][jn][r] + bval);
                }
        }
        __syncthreads();
        const int bi = m0 >> 11, t0 = m0 & (T_ - 1);
        #pragma unroll
        for (int i = 0; i < 4; ++i) {
            int cidx = i * 256 + tid;
            int n = cidx >> 3, cc = cidx & 7;
            *(uint4*)&vo[((size_t)(bi * H_ + n)) * T_ + t0 + cc * 8] =
                *(const uint4*)&eb[n * 64 + cc * 8];
        }
    }
}

// ---------------------------------------------------------------------------
// attn_split6: KV-split flash attention. chunk=256 keys -> 288 jobs/batch,
// grid (8 batch=XCD pin, 288). QBLK=32 (2 waves), KVBLK=32.
// K staged in LDS via gload16 dbuf; V in LOOP-CARRIED register double-buffer
// (vfA/vfB loaded for tile t+1 during tile t -> compiler cannot sink).
// LDS = K 16KB + P 4KB = 20KB. launch_bounds(128,3) -> ~6 blocks/CU resident.
// No-max exp2 softmax; partials stored bf16.
// ---------------------------------------------------------------------------
__global__ __launch_bounds__(128, 3) void attn_split6(
    const unsigned short* __restrict__ q,
    const unsigned short* __restrict__ k,
    const unsigned short* __restrict__ vT,
    float* __restrict__ out,
    unsigned short* __restrict__ Opart, float* __restrict__ lws)
{
    const int bb = blockIdx.x;                 // batch -> XCD pin
    const int jj = 287 - (int)blockIdx.y;      // longest jobs first
    int g;
    if (jj < 8)        g = 0;
    else if (jj < 24)  g = 1;
    else if (jj < 48)  g = 2;
    else if (jj < 80)  g = 3;
    else if (jj < 120) g = 4;
    else if (jj < 168) g = 5;
    else if (jj < 224) g = 6;
    else               g = 7;
    const int rel = jj - 4 * g * (g + 1);
    const int dq = rel / (g + 1);
    const int c = rel - dq * (g + 1);
    const int qt = 8 * g + dq;
    const int q0 = qt * 32;
    const int kstart = c * 256;
    const int kend = min(kstart + 256, q0 + 32);
    const int ntiles = (kend - kstart) >> 5;   // 1..8

    const unsigned short* qb = q  + (size_t)bb * T_ * H_;
    const unsigned short* kb = k  + (size_t)bb * T_ * H_;
    const unsigned short* vb = vT + (size_t)bb * H_ * T_;

    __shared__ unsigned short Ks[2][32 * 128];   // 16 KB, chunk-XOR swizzled
    __shared__ unsigned short Ps[2][16 * 64];    // 4 KB, per-wave

    const int tid = threadIdx.x;
    const int w = tid >> 6, l = tid & 63, gl = l >> 4, lc = l & 15;

    bf16x8 aq[4];
    #pragma unroll
    for (int ds = 0; ds < 4; ++ds)
        aq[ds] = *(const bf16x8*)&qb[(size_t)(q0 + w * 16 + lc) * H_ + ds * 32 + gl * 8];

    f32x4 o[8];
    #pragma unroll
    for (int jo = 0; jo < 8; ++jo) o[jo] = f32x4{0.f, 0.f, 0.f, 0.f};
    float l_acc[4];
    #pragma unroll
    for (int r = 0; r < 4; ++r) l_acc[r] = 0.f;

    auto stageK = [&](int buf, int t) {
        const int kv0 = kstart + t * 32;
        #pragma unroll
        for (int ji = 0; ji < 4; ++ji) {
            int slot = (w * 4 + ji) * 64 + l;          // 0..511 (16B units)
            int r = slot >> 4, cs = slot & 15;
            gload16(&Ks[buf][((w * 4 + ji) * 64) * 8],
                    &kb[(size_t)(kv0 + r) * H_ + ((cs ^ (r & 7)) * 8)]);
        }
    };

    const unsigned short* vrow = vb + (size_t)lc * T_ + kstart + gl * 8;

    bf16x8 vfA[8], vfB[8];
    #pragma unroll
    for (int jo = 0; jo < 8; ++jo)
        vfA[jo] = *(const bf16x8*)(vrow + (size_t)jo * 16 * T_);
    stageK(0, 0);
    __syncthreads();

    auto body = [&](int t, int buf, bf16x8 (&vcur)[8], bf16x8 (&vnext)[8]) {
        const int kv0 = kstart + t * 32;
        if (t + 1 < ntiles) {
            // loop-carried V prefetch for next tile (forces early issue)
            #pragma unroll
            for (int jo = 0; jo < 8; ++jo)
                vnext[jo] = *(const bf16x8*)(vrow + (size_t)jo * 16 * T_ + (t + 1) * 32);
            stageK(buf ^ 1, t + 1);
        }
        // S = Q K^T from LDS
        f32x4 s[2];
        #pragma unroll
        for (int jk = 0; jk < 2; ++jk) s[jk] = f32x4{0.f, 0.f, 0.f, 0.f};
        #pragma unroll
        for (int ds = 0; ds < 4; ++ds) {
            #pragma unroll
            for (int jk = 0; jk < 2; ++jk) {
                int row = jk * 16 + lc;
                bf16x8 kf = *(const bf16x8*)&Ks[buf][(row * 16 + ((ds * 4 + gl) ^ (row & 7))) * 8];
                s[jk] = __builtin_amdgcn_mfma_f32_16x16x32_bf16(aq[ds], kf, s[jk], 0, 0, 0);
            }
        }
        // causal mask: only the diagonal tile (last tile of last chunk)
        if (kv0 == q0) {
            #pragma unroll
            for (int jk = 0; jk < 2; ++jk)
                #pragma unroll
                for (int r = 0; r < 4; ++r)
                    if (jk * 16 + lc > w * 16 + gl * 4 + r) s[jk][r] = -1e30f;
        }
        // p = exp2(s); l lane-partials
        #pragma unroll
        for (int jk = 0; jk < 2; ++jk)
            #pragma unroll
            for (int r = 0; r < 4; ++r) {
                float p = exp2f(fminf(s[jk][r], 80.f));
                s[jk][r] = p;
                l_acc[r] += p;
            }
        // P -> per-wave LDS (same-wave RAW)
        #pragma unroll
        for (int jk = 0; jk < 2; ++jk)
            #pragma unroll
            for (int r = 0; r < 4; ++r) {
                int row = gl * 4 + r;
                Ps[w][(row * 64 + jk * 16 + lc) ^ ((row & 7) << 3)] = f2bf(s[jk][r]);
            }
        // O += P @ V with register V
        {
            bf16x8 pa = *(const bf16x8*)&Ps[w][(lc * 64 + gl * 8) ^ ((lc & 7) << 3)];
            #pragma unroll
            for (int jo = 0; jo < 8; ++jo)
                o[jo] = __builtin_amdgcn_mfma_f32_16x16x32_bf16(pa, vcur[jo], o[jo], 0, 0, 0);
        }
        __syncthreads();
    };

    int t = 0;
    while (true) {
        body(t, 0, vfA, vfB); ++t; if (t == ntiles) break;
        body(t, 1, vfB, vfA); ++t; if (t == ntiles) break;
    }

    // reduce l over the 16 key-lanes (once per job)
    #pragma unroll
    for (int off = 1; off < 16; off <<= 1)
        #pragma unroll
        for (int r = 0; r < 4; ++r)
            l_acc[r] += __shfl_xor(l_acc[r], off, 64);

    if (g == 0) {
        // single-chunk job: write normalized output directly
        float* ob = out + (size_t)bb * T_ * H_;
        float inv[4];
        #pragma unroll
        for (int r = 0; r < 4; ++r) inv[r] = 1.0f / l_acc[r];
        #pragma unroll
        for (int jo = 0; jo < 8; ++jo)
            #pragma unroll
            for (int r = 0; r < 4; ++r)
                ob[(size_t)(q0 + w * 16 + gl * 4 + r) * H_ + jo * 16 + lc] = o[jo][r] * inv[r];
    } else {
        const int ps = bb * 280 + (jj - 8);
        unsigned short* op = Opart + (size_t)ps * 4096;
        #pragma unroll
        for (int jo = 0; jo < 8; ++jo)
            #pragma unroll
            for (int r = 0; r < 4; ++r)
                op[(w * 16 + gl * 4 + r) * 128 + jo * 16 + lc] = f2bf(o[jo][r]);
        if (lc == 0) {
            #pragma unroll
            for (int r = 0; r < 4; ++r)
                lws[ps * 32 + w * 16 + gl * 4 + r] = l_acc[r];
        }
    }
}

// ---------------------------------------------------------------------------
// combine: out[t] = sum_c O_c[t] / sum_c l_c[t] for t >= 256 (bf16 partials).
// 4 rows/block, 64 lanes/row (2 elems each). 14336 rows total.
// ---------------------------------------------------------------------------
__global__ __launch_bounds__(256) void combine_kernel(
    const unsigned short* __restrict__ Opart, const float* __restrict__ lws,
    float* __restrict__ out)
{
    const int rowid = blockIdx.x * 4 + (threadIdx.x >> 6);   // 0..14335
    const int lane = threadIdx.x & 63;
    const int bb = rowid / 1792;
    const int t = 256 + (rowid - bb * 1792);
    const int qt = t >> 5;                                    // 8..63
    const int g = qt >> 3;                                    // 1..7
    const int nch = g + 1;
    const int j0 = 4 * g * (g + 1) + (qt - 8 * g) * (g + 1);
    const int base = bb * 280 + (j0 - 8);
    const int r32 = t & 31;

    float L = 0.f, a0 = 0.f, a1 = 0.f;
    #pragma unroll
    for (int c2 = 0; c2 < 8; ++c2)
        if (c2 < nch) {
            L += lws[(base + c2) * 32 + r32];
            ushort2 uv = *(const ushort2*)&Opart[(size_t)(base + c2) * 4096 + r32 * 128 + lane * 2];
            a0 += bf2f(uv.x); a1 += bf2f(uv.y);
        }
    const float invL = 1.0f / L;
    *(float2*)&out[((size_t)bb * T_ + t) * H_ + lane * 2] = make_float2(a0 * invL, a1 * invL);
}

// ---------------------------------------------------------------------------
// Fallback monolithic attention (only if ws too small). Max-tracking version.
// ---------------------------------------------------------------------------
__global__ __launch_bounds__(128) void attn_mono(
    const unsigned short* __restrict__ q,
    const unsigned short* __restrict__ k,
    const unsigned short* __restrict__ vT,
    float* __restrict__ out)
{
    const int qt = (gridDim.x - 1) - blockIdx.x;
    const int bb = blockIdx.y;
    const int q0 = qt * 32;
    const unsigned short* qb = q  + (size_t)bb * T_ * H_;
    const unsigned short* kb = k  + (size_t)bb * T_ * H_;
    const unsigned short* vb = vT + (size_t)bb * H_ * T_;

    __shared__ unsigned short Ps[2][16 * 64];

    const int tid = threadIdx.x;
    const int w = tid >> 6, l = tid & 63, gl = l >> 4, lc = l & 15;

    bf16x8 aq[4];
    #pragma unroll
    for (int ds = 0; ds < 4; ++ds)
        aq[ds] = *(const bf16x8*)&qb[(size_t)(q0 + w * 16 + lc) * H_ + ds * 32 + gl * 8];

    f32x4 o[8];
    #pragma unroll
    for (int jo = 0; jo < 8; ++jo) o[jo] = f32x4{0.f, 0.f, 0.f, 0.f};
    float m_run[4], l_run[4];
    #pragma unroll
    for (int r = 0; r < 4; ++r) { m_run[r] = -INFINITY; l_run[r] = 0.f; }

    const int nt = (q0 >> 6) + 1;
    for (int t = 0; t < nt; ++t) {
        const int kv0 = t * 64;
        f32x4 s[4];
        #pragma unroll
        for (int jk = 0; jk < 4; ++jk) s[jk] = f32x4{0.f, 0.f, 0.f, 0.f};
        #pragma unroll
        for (int ds = 0; ds < 4; ++ds)
            #pragma unroll
            for (int jk = 0; jk < 4; ++jk) {
                bf16x8 bf = *(const bf16x8*)&kb[(size_t)(kv0 + jk * 16 + lc) * H_ + ds * 32 + gl * 8];
                s[jk] = __builtin_amdgcn_mfma_f32_16x16x32_bf16(aq[ds], bf, s[jk], 0, 0, 0);
            }
        if (kv0 + 63 > q0) {
            const int rowg = q0 + w * 16 + gl * 4;
            #pragma unroll
            for (int jk = 0; jk < 4; ++jk)
                #pragma unroll
                for (int r = 0; r < 4; ++r)
                    if (kv0 + jk * 16 + lc > rowg + r) s[jk][r] = -1e30f;
        }
        float pm[4];
        #pragma unroll
        for (int r = 0; r < 4; ++r)
            pm[r] = fmaxf(fmaxf(s[0][r], s[1][r]), fmaxf(s[2][r], s[3][r]));
        #pragma unroll
        for (int off = 1; off < 16; off <<= 1)
            #pragma unroll
            for (int r = 0; r < 4; ++r)
                pm[r] = fmaxf(pm[r], __shfl_xor(pm[r], off, 64));
        float scl[4], rs[4];
        #pragma unroll
        for (int r = 0; r < 4; ++r) {
            float mn = fmaxf(m_run[r], pm[r]);
            scl[r] = exp2f(m_run[r] - mn);
            m_run[r] = mn;
            rs[r] = 0.f;
        }
        #pragma unroll
        for (int jk = 0; jk < 4; ++jk)
            #pragma unroll
            for (int r = 0; r < 4; ++r) {
                float p = exp2f(s[jk][r] - m_run[r]);
                s[jk][r] = p;
                rs[r] += p;
            }
        #pragma unroll
        for (int off = 1; off < 16; off <<= 1)
            #pragma unroll
            for (int r = 0; r < 4; ++r)
                rs[r] += __shfl_xor(rs[r], off, 64);
        #pragma unroll
        for (int r = 0; r < 4; ++r)
            l_run[r] = l_run[r] * scl[r] + rs[r];
        #pragma unroll
        for (int jo = 0; jo < 8; ++jo)
            #pragma unroll
            for (int r = 0; r < 4; ++r)
                o[jo][r] *= scl[r];
        #pragma unroll
        for (int jk = 0; jk < 4; ++jk)
            #pragma unroll
            for (int r = 0; r < 4; ++r) {
                int row = gl * 4 + r;
                Ps[w][(row * 64 + jk * 16 + lc) ^ ((row & 7) << 3)] = f2bf(s[jk][r]);
            }
        #pragma unroll
        for (int ks = 0; ks < 2; ++ks) {
            bf16x8 pa = *(const bf16x8*)&Ps[w][(lc * 64 + ks * 32 + gl * 8) ^ ((lc & 7) << 3)];
            #pragma unroll
            for (int jo = 0; jo < 8; ++jo) {
                bf16x8 bv_ = *(const bf16x8*)&vb[(size_t)(jo * 16 + lc) * T_ + kv0 + ks * 32 + gl * 8];
                o[jo] = __builtin_amdgcn_mfma_f32_16x16x32_bf16(pa, bv_, o[jo], 0, 0, 0);
            }
        }
    }
    float* ob = out + (size_t)bb * T_ * H_;
    #pragma unroll
    for (int jo = 0; jo < 8; ++jo)
        #pragma unroll
        for (int r = 0; r < 4; ++r)
            ob[(size_t)(q0 + w * 16 + gl * 4 + r) * H_ + jo * 16 + lc] = o[jo][r] / l_run[r];
}

extern "C" void kernel_launch(void* const* d_in, const int* in_sizes, int n_in,
                              void* d_out, int out_size, void* d_ws, size_t ws_size,
                              hipStream_t stream) {
    const float* x  = (const float*)d_in[0];
    const float* Wq = (const float*)d_in[1];
    const float* bq = (const float*)d_in[2];
    const float* Wk = (const float*)d_in[3];
    const float* bk = (const float*)d_in[4];
    const float* Wv = (const float*)d_in[5];
    const float* bv = (const float*)d_in[6];
    float* out = (float*)d_out;

    const size_t qkv = (size_t)B_ * T_ * H_;               // 2M elems
    unsigned short* qws = (unsigned short*)d_ws;
    unsigned short* kws = qws + qkv;
    unsigned short* vws = kws + qkv;                       // [B,H,T] transposed
    unsigned short* wtw = vws + qkv;                       // [3,H,C]
    const size_t base_bytes = (3 * qkv + (size_t)3 * H_ * C_) * 2;  // 13,369,344
    unsigned short* Opart = (unsigned short*)((char*)d_ws + base_bytes);  // 2240 x 4096 bf16
    float* lws = (float*)((char*)d_ws + base_bytes + (size_t)2240 * 4096 * 2);
    const size_t need = base_bytes + (size_t)2240 * 4096 * 2 + (size_t)2240 * 32 * 4;

    prep_w<<<dim3(192), 256, 0, stream>>>(Wq, Wk, Wv, wtw);
    proj_kernel<<<dim3(256, 3), 256, 0, stream>>>(x, wtw, bq, bk, bv, qws, kws, vws);
    if (ws_size >= need) {
        attn_split6<<<dim3(8, 288), 128, 0, stream>>>(qws, kws, vws, out, Opart, lws);
        combine_kernel<<<dim3(3584), 256, 0, stream>>>(Opart, lws, out);
    } else {
        attn_mono<<<dim3(64, 8), 128, 0, stream>>>(qws, kws, vws, out);
    }
}

// Round 9
// 80.110 us; speedup vs baseline: 1.8695x; 1.8695x over previous
//
#include <hip/hip_runtime.h>
#include <cstdint>
#include <cstddef>

typedef __bf16 bf16x8 __attribute__((ext_vector_type(8)));
typedef float f32x4 __attribute__((ext_vector_type(4)));

#define B_ 8
#define T_ 2048
#define C_ 1024
#define H_ 128

// C^-0.5 * log2(e): folded into Q at projection; softmax runs in exp2-space.
#define QSC 0.045084220027780106f

__device__ __forceinline__ unsigned short f2bf(float f) {
    __bf16 h = (__bf16)f;
    return *(unsigned short*)&h;
}
__device__ __forceinline__ float bf2f(unsigned short u) {
    union { unsigned int i; float f; } x; x.i = ((unsigned int)u) << 16;
    return x.f;
}

// async global->LDS, 16B per lane. LDS dest must be the wave-uniform base;
// HW adds lane*16. Global src is per-lane.
__device__ __forceinline__ void gload16(void* lds, const void* g) {
    __builtin_amdgcn_global_load_lds(
        (const __attribute__((address_space(1))) unsigned int*)g,
        (__attribute__((address_space(3))) unsigned int*)lds, 16, 0, 0);
}

// ---------------------------------------------------------------------------
// prep_w: WT[which][n][k] bf16  <-  W[k][n] f32.
// ---------------------------------------------------------------------------
__global__ __launch_bounds__(256) void prep_w(
    const float* __restrict__ Wq, const float* __restrict__ Wk,
    const float* __restrict__ Wv, unsigned short* __restrict__ wt)
{
    int gid = blockIdx.x * 256 + threadIdx.x;        // 49152 total
    int which = gid >> 14;
    int rem = gid & 16383;
    int n = rem >> 7;            // 0..127
    int kc = rem & 127;          // k-chunk of 8
    const float* W = which == 0 ? Wq : (which == 1 ? Wk : Wv);
    unsigned short tmp[8];
    #pragma unroll
    for (int i = 0; i < 8; ++i) tmp[i] = f2bf(W[(size_t)(kc * 8 + i) * H_ + n]);
    *(uint4*)&wt[((size_t)which * H_ + n) * C_ + kc * 8] = *(uint4*)tmp;
}

// ---------------------------------------------------------------------------
// proj: out = x @ W + b. x staged as F32 via gload16 (fire-and-forget, no
// VGPR roundtrip); converted to bf16 at fragment-load time. BM=64, BN=128,
// BK=64, 4 waves, double-buffered. LDS 64KB -> 2 blocks/CU.
// Q pre-scaled by QSC; V stored transposed [B,H,T].
// ---------------------------------------------------------------------------
__global__ __launch_bounds__(256) void proj_kernel(
    const float* __restrict__ x, const unsigned short* __restrict__ wt,
    const float* __restrict__ bq, const float* __restrict__ bk,
    const float* __restrict__ bv,
    unsigned short* __restrict__ qo, unsigned short* __restrict__ ko,
    unsigned short* __restrict__ vo)
{
    const int which = blockIdx.y;
    const float* bias = which == 0 ? bq : (which == 1 ? bk : bv);

    __shared__ float xs[2][64 * 64];             // [m][k] f32, unit-XOR swizzled
    __shared__ unsigned short ws2[2][128 * 64];  // [n][k] bf16, chunk-XOR swizzled

    const int tid = threadIdx.x;
    const int w = tid >> 6, l = tid & 63, g = l >> 4, lc = l & 15;
    const int wm = w & 1, wn = w >> 1;
    const int m0 = blockIdx.x * 64;

    const unsigned short* wbase = &wt[(size_t)which * H_ * C_];

    f32x4 acc[2][4];
    #pragma unroll
    for (int im = 0; im < 2; ++im)
        #pragma unroll
        for (int jn = 0; jn < 4; ++jn) acc[im][jn] = f32x4{0.f, 0.f, 0.f, 0.f};

    auto stage = [&](int buf, int kc2) {
        const int kb = kc2 * 64;
        #pragma unroll
        for (int jj = 0; jj < 4; ++jj) {
            int slot = w * 256 + jj * 64 + l;
            int r = slot >> 3, cs = slot & 7;
            gload16(&ws2[buf][(w * 256 + jj * 64) * 8],
                    &wbase[(size_t)r * C_ + kb + ((cs ^ (r & 7)) * 8)]);
        }
        #pragma unroll
        for (int jj = 0; jj < 4; ++jj) {
            int slot = w * 256 + jj * 64 + l;
            int r = slot >> 4, cs = slot & 15;
            gload16(&xs[buf][(w * 256 + jj * 64) * 4],
                    &x[(size_t)(m0 + r) * C_ + kb + ((cs ^ (r & 15)) * 4)]);
        }
    };

    stage(0, 0);
    __syncthreads();

    int cur = 0;
    for (int kc = 0; kc < 16; ++kc) {
        if (kc < 15) stage(cur ^ 1, kc + 1);
        #pragma unroll
        for (int ks = 0; ks < 2; ++ks) {
            bf16x8 a[2], b[4];
            #pragma unroll
            for (int im = 0; im < 2; ++im) {
                int row = wm * 32 + im * 16 + lc;
                int u0 = ks * 8 + g * 2;
                f32x4 lo = *(const f32x4*)&xs[cur][(row * 16 + (u0 ^ (row & 15))) * 4];
                f32x4 hi = *(const f32x4*)&xs[cur][(row * 16 + ((u0 + 1) ^ (row & 15))) * 4];
                bf16x8 af;
                af[0] = (__bf16)lo[0]; af[1] = (__bf16)lo[1];
                af[2] = (__bf16)lo[2]; af[3] = (__bf16)lo[3];
                af[4] = (__bf16)hi[0]; af[5] = (__bf16)hi[1];
                af[6] = (__bf16)hi[2]; af[7] = (__bf16)hi[3];
                a[im] = af;
            }
            #pragma unroll
            for (int jn = 0; jn < 4; ++jn) {
                int n = wn * 64 + jn * 16 + lc;
                b[jn] = *(const bf16x8*)&ws2[cur][(n * 8 + ((ks * 4 + g) ^ (n & 7))) * 8];
            }
            #pragma unroll
            for (int im = 0; im < 2; ++im)
                #pragma unroll
                for (int jn = 0; jn < 4; ++jn)
                    acc[im][jn] = __builtin_amdgcn_mfma_f32_16x16x32_bf16(
                        a[im], b[jn], acc[im][jn], 0, 0, 0);
        }
        __syncthreads();
        cur ^= 1;
    }

    unsigned short* eb = (unsigned short*)&xs[0][0];
    if (which != 2) {
        const float osc = (which == 0) ? QSC : 1.0f;
        #pragma unroll
        for (int jn = 0; jn < 4; ++jn) {
            int n = wn * 64 + jn * 16 + lc;
            float bval = bias[n];
            #pragma unroll
            for (int im = 0; im < 2; ++im)
                #pragma unroll
                for (int r = 0; r < 4; ++r) {
                    int ml = wm * 32 + im * 16 + g * 4 + r;
                    eb[ml * 128 + n] = f2bf((acc[im][jn][r] + bval) * osc);
                }
        }
        __syncthreads();
        unsigned short* o = which == 0 ? qo : ko;
        #pragma unroll
        for (int i = 0; i < 4; ++i) {
            int cidx = i * 256 + tid;
            int row = cidx >> 4, c16 = cidx & 15;
            *(uint4*)&o[(size_t)(m0 + row) * H_ + c16 * 8] =
                *(const uint4*)&eb[row * 128 + c16 * 8];
        }
    } else {
        #pragma unroll
        for (int jn = 0; jn < 4; ++jn) {
            int n = wn * 64 + jn * 16 + lc;
            float bval = bias[n];
            #pragma unroll
            for (int im = 0; im < 2; ++im)
                #pragma unroll
                for (int r = 0; r < 4; ++r) {
                    int ml = wm * 32 + im * 16 + g * 4 + r;
                    eb[n * 64 + ml] = f2bf(acc[im][jn][r] + bval);
                }
        }
        __syncthreads();
        const int bi = m0 >> 11, t0 = m0 & (T_ - 1);
        #pragma unroll
        for (int i = 0; i < 4; ++i) {
            int cidx = i * 256 + tid;
            int n = cidx >> 3, cc = cidx & 7;
            *(uint4*)&vo[((size_t)(bi * H_ + n)) * T_ + t0 + cc * 8] =
                *(const uint4*)&eb[n * 64 + cc * 8];
        }
    }
}

// pasc(qt) = number of jobs for q-tiles < qt (QBLK=64, chunk=256):
// nch(i) = ceil((i+1)/4); pasc = 2m(m+1) + j(m+1), m=qt>>2, j=qt&3.
__device__ __forceinline__ int pasc(int qt) {
    int m = qt >> 2, j = qt & 3;
    return 2 * m * (m + 1) + j * (m + 1);
}

// ---------------------------------------------------------------------------
// attn_split7: KV-split flash attention, 4 waves (QBLK=64) sharing K/V LDS.
// grid (8 batch=XCD pin, 144 jobs). KVBLK=32, chunk=256 keys.
// K [32][128] + V [128][32] staged via fire-and-forget gload16, dbuf.
// LDS = 16+16+8 = 40KB -> 4 blocks/CU = 16 waves/CU resident.
// Per-wave uniform skip of fully-masked diagonal tiles. No-max exp2
// softmax; bf16 partials; plain-sum combine.
// ---------------------------------------------------------------------------
__global__ __launch_bounds__(256, 2) void attn_split7(
    const unsigned short* __restrict__ q,
    const unsigned short* __restrict__ k,
    const unsigned short* __restrict__ vT,
    float* __restrict__ out,
    unsigned short* __restrict__ Opart, float* __restrict__ lws)
{
    const int bb = blockIdx.x;                 // batch -> XCD pin
    const int jj = 143 - (int)blockIdx.y;      // longest jobs first
    int qt = 31;
    while (pasc(qt) > jj) --qt;
    const int c = jj - pasc(qt);
    const int nch = (qt >> 2) + 1;
    const int q0 = qt * 64;
    const int kstart = c * 256;
    const int kend = min(kstart + 256, q0 + 64);
    const int ntiles = (kend - kstart) >> 5;   // 1..8

    const unsigned short* qb = q  + (size_t)bb * T_ * H_;
    const unsigned short* kb = k  + (size_t)bb * T_ * H_;
    const unsigned short* vb = vT + (size_t)bb * H_ * T_;

    __shared__ unsigned short Ks[2][32 * 128];   // [key][d], chunk-XOR swizzled
    __shared__ unsigned short Vs[2][128 * 32];   // [d][key], chunk-XOR swizzled
    __shared__ unsigned short Ps[4][16 * 64];    // per-wave P

    const int tid = threadIdx.x;
    const int w = tid >> 6, l = tid & 63, gl = l >> 4, lc = l & 15;
    const int rowbase = q0 + w * 16;             // this wave's first q row

    bf16x8 aq[4];
    #pragma unroll
    for (int ds = 0; ds < 4; ++ds)
        aq[ds] = *(const bf16x8*)&qb[(size_t)(rowbase + lc) * H_ + ds * 32 + gl * 8];

    f32x4 o[8];
    #pragma unroll
    for (int jo = 0; jo < 8; ++jo) o[jo] = f32x4{0.f, 0.f, 0.f, 0.f};
    float l_acc[4];
    #pragma unroll
    for (int r = 0; r < 4; ++r) l_acc[r] = 0.f;

    // K tile: 512 16B units over 256 threads (2 each)
    auto stageK = [&](int buf, int t) {
        const int kv0 = kstart + t * 32;
        #pragma unroll
        for (int ji = 0; ji < 2; ++ji) {
            int slot = (w * 2 + ji) * 64 + l;
            int r = slot >> 4, cs = slot & 15;
            gload16(&Ks[buf][((w * 2 + ji) * 64) * 8],
                    &kb[(size_t)(kv0 + r) * H_ + ((cs ^ (r & 7)) * 8)]);
        }
    };
    // V tile: 512 16B units
    auto stageV = [&](int buf, int t) {
        const int kv0 = kstart + t * 32;
        #pragma unroll
        for (int ji = 0; ji < 2; ++ji) {
            int slot = (w * 2 + ji) * 64 + l;
            int r = slot >> 2, cs = slot & 3;
            gload16(&Vs[buf][((w * 2 + ji) * 64) * 8],
                    &vb[(size_t)r * T_ + kv0 + ((cs ^ (r & 3)) * 8)]);
        }
    };

    stageK(0, 0);
    stageV(0, 0);
    __syncthreads();

    int cur = 0;
    for (int t = 0; t < ntiles; ++t) {
        if (t + 1 < ntiles) { stageK(cur ^ 1, t + 1); stageV(cur ^ 1, t + 1); }
        const int kv0 = kstart + t * 32;
        // wave-uniform: skip tiles fully above this wave's causal limit
        const bool active = kv0 < rowbase + 16;
        if (active) {
            // S = Q K^T from LDS
            f32x4 s[2];
            #pragma unroll
            for (int jk = 0; jk < 2; ++jk) s[jk] = f32x4{0.f, 0.f, 0.f, 0.f};
            #pragma unroll
            for (int ds = 0; ds < 4; ++ds) {
                #pragma unroll
                for (int jk = 0; jk < 2; ++jk) {
                    int row = jk * 16 + lc;
                    bf16x8 kf = *(const bf16x8*)&Ks[cur][(row * 16 + ((ds * 4 + gl) ^ (row & 7))) * 8];
                    s[jk] = __builtin_amdgcn_mfma_f32_16x16x32_bf16(aq[ds], kf, s[jk], 0, 0, 0);
                }
            }
            // causal mask where the tile crosses this wave's rows
            if (kv0 + 31 > rowbase) {
                #pragma unroll
                for (int jk = 0; jk < 2; ++jk)
                    #pragma unroll
                    for (int r = 0; r < 4; ++r)
                        if (kv0 + jk * 16 + lc > rowbase + gl * 4 + r) s[jk][r] = -1e30f;
            }
            // p = exp2(s); l lane-partials
            #pragma unroll
            for (int jk = 0; jk < 2; ++jk)
                #pragma unroll
                for (int r = 0; r < 4; ++r) {
                    float p = exp2f(fminf(s[jk][r], 80.f));
                    s[jk][r] = p;
                    l_acc[r] += p;
                }
            // P -> per-wave LDS (same-wave RAW)
            #pragma unroll
            for (int jk = 0; jk < 2; ++jk)
                #pragma unroll
                for (int r = 0; r < 4; ++r) {
                    int row = gl * 4 + r;
                    Ps[w][(row * 64 + jk * 16 + lc) ^ ((row & 7) << 3)] = f2bf(s[jk][r]);
                }
            // O += P @ V from LDS
            {
                bf16x8 pa = *(const bf16x8*)&Ps[w][(lc * 64 + gl * 8) ^ ((lc & 7) << 3)];
                #pragma unroll
                for (int jo = 0; jo < 8; ++jo) {
                    int d = jo * 16 + lc;
                    bf16x8 vf = *(const bf16x8*)&Vs[cur][(d * 4 + (gl ^ (d & 3))) * 8];
                    o[jo] = __builtin_amdgcn_mfma_f32_16x16x32_bf16(pa, vf, o[jo], 0, 0, 0);
                }
            }
        }
        __syncthreads();
        cur ^= 1;
    }

    // reduce l over the 16 key-lanes (once per job)
    #pragma unroll
    for (int off = 1; off < 16; off <<= 1)
        #pragma unroll
        for (int r = 0; r < 4; ++r)
            l_acc[r] += __shfl_xor(l_acc[r], off, 64);

    if (nch == 1) {
        // single-chunk job (qt<=3): write normalized output directly
        float* ob = out + (size_t)bb * T_ * H_;
        float inv[4];
        #pragma unroll
        for (int r = 0; r < 4; ++r) inv[r] = 1.0f / l_acc[r];
        #pragma unroll
        for (int jo = 0; jo < 8; ++jo)
            #pragma unroll
            for (int r = 0; r < 4; ++r)
                ob[(size_t)(rowbase + gl * 4 + r) * H_ + jo * 16 + lc] = o[jo][r] * inv[r];
    } else {
        const int slot = bb * 140 + (pasc(qt) - 4 + c);
        unsigned short* op = Opart + (size_t)slot * 8192;
        #pragma unroll
        for (int jo = 0; jo < 8; ++jo)
            #pragma unroll
            for (int r = 0; r < 4; ++r)
                op[(w * 16 + gl * 4 + r) * 128 + jo * 16 + lc] = f2bf(o[jo][r]);
        if (lc == 0) {
            #pragma unroll
            for (int r = 0; r < 4; ++r)
                lws[slot * 64 + w * 16 + gl * 4 + r] = l_acc[r];
        }
    }
}

// ---------------------------------------------------------------------------
// combine: out[t] = sum_c O_c[t] / sum_c l_c[t] for t >= 256 (bf16 partials).
// 4 rows/block, 64 lanes/row (2 elems each). 14336 rows total.
// ---------------------------------------------------------------------------
__global__ __launch_bounds__(256) void combine_kernel(
    const unsigned short* __restrict__ Opart, const float* __restrict__ lws,
    float* __restrict__ out)
{
    const int rowid = blockIdx.x * 4 + (threadIdx.x >> 6);   // 0..14335
    const int lane = threadIdx.x & 63;
    const int bb = rowid / 1792;
    const int t = 256 + (rowid - bb * 1792);                 // 256..2047
    const int qt = t >> 6;                                    // 4..31
    const int m = qt >> 2;
    const int nch = m + 1;
    const int p0 = 2 * m * (m + 1) + (qt & 3) * (m + 1);     // pasc(qt)
    const int base = bb * 140 + (p0 - 4);
    const int r64 = t & 63;

    float L = 0.f, a0 = 0.f, a1 = 0.f;
    #pragma unroll
    for (int c2 = 0; c2 < 8; ++c2)
        if (c2 < nch) {
            L += lws[(base + c2) * 64 + r64];
            ushort2 uv = *(const ushort2*)&Opart[(size_t)(base + c2) * 8192 + r64 * 128 + lane * 2];
            a0 += bf2f(uv.x); a1 += bf2f(uv.y);
        }
    const float invL = 1.0f / L;
    *(float2*)&out[((size_t)bb * T_ + t) * H_ + lane * 2] = make_float2(a0 * invL, a1 * invL);
}

// ---------------------------------------------------------------------------
// Fallback monolithic attention (only if ws too small). Max-tracking version.
// ---------------------------------------------------------------------------
__global__ __launch_bounds__(128) void attn_mono(
    const unsigned short* __restrict__ q,
    const unsigned short* __restrict__ k,
    const unsigned short* __restrict__ vT,
    float* __restrict__ out)
{
    const int qt = (gridDim.x - 1) - blockIdx.x;
    const int bb = blockIdx.y;
    const int q0 = qt * 32;
    const unsigned short* qb = q  + (size_t)bb * T_ * H_;
    const unsigned short* kb = k  + (size_t)bb * T_ * H_;
    const unsigned short* vb = vT + (size_t)bb * H_ * T_;

    __shared__ unsigned short Ps[2][16 * 64];

    const int tid = threadIdx.x;
    const int w = tid >> 6, l = tid & 63, gl = l >> 4, lc = l & 15;

    bf16x8 aq[4];
    #pragma unroll
    for (int ds = 0; ds < 4; ++ds)
        aq[ds] = *(const bf16x8*)&qb[(size_t)(q0 + w * 16 + lc) * H_ + ds * 32 + gl * 8];

    f32x4 o[8];
    #pragma unroll
    for (int jo = 0; jo < 8; ++jo) o[jo] = f32x4{0.f, 0.f, 0.f, 0.f};
    float m_run[4], l_run[4];
    #pragma unroll
    for (int r = 0; r < 4; ++r) { m_run[r] = -INFINITY; l_run[r] = 0.f; }

    const int nt = (q0 >> 6) + 1;
    for (int t = 0; t < nt; ++t) {
        const int kv0 = t * 64;
        f32x4 s[4];
        #pragma unroll
        for (int jk = 0; jk < 4; ++jk) s[jk] = f32x4{0.f, 0.f, 0.f, 0.f};
        #pragma unroll
        for (int ds = 0; ds < 4; ++ds)
            #pragma unroll
            for (int jk = 0; jk < 4; ++jk) {
                bf16x8 bf = *(const bf16x8*)&kb[(size_t)(kv0 + jk * 16 + lc) * H_ + ds * 32 + gl * 8];
                s[jk] = __builtin_amdgcn_mfma_f32_16x16x32_bf16(aq[ds], bf, s[jk], 0, 0, 0);
            }
        if (kv0 + 63 > q0) {
            const int rowg = q0 + w * 16 + gl * 4;
            #pragma unroll
            for (int jk = 0; jk < 4; ++jk)
                #pragma unroll
                for (int r = 0; r < 4; ++r)
                    if (kv0 + jk * 16 + lc > rowg + r) s[jk][r] = -1e30f;
        }
        float pm[4];
        #pragma unroll
        for (int r = 0; r < 4; ++r)
            pm[r] = fmaxf(fmaxf(s[0][r], s[1][r]), fmaxf(s[2][r], s[3][r]));
        #pragma unroll
        for (int off = 1; off < 16; off <<= 1)
            #pragma unroll
            for (int r = 0; r < 4; ++r)
                pm[r] = fmaxf(pm[r], __shfl_xor(pm[r], off, 64));
        float scl[4], rs[4];
        #pragma unroll
        for (int r = 0; r < 4; ++r) {
            float mn = fmaxf(m_run[r], pm[r]);
            scl[r] = exp2f(m_run[r] - mn);
            m_run[r] = mn;
            rs[r] = 0.f;
        }
        #pragma unroll
        for (int jk = 0; jk < 4; ++jk)
            #pragma unroll
            for (int r = 0; r < 4; ++r) {
                float p = exp2f(s[jk][r] - m_run[r]);
                s[jk][r] = p;
                rs[r] += p;
            }
        #pragma unroll
        for (int off = 1; off < 16; off <<= 1)
            #pragma unroll
            for (int r = 0; r < 4; ++r)
                rs[r] += __shfl_xor(rs[r], off, 64);
        #pragma unroll
        for (int r = 0; r < 4; ++r)
            l_run[r] = l_run[r] * scl[r] + rs[r];
        #pragma unroll
        for (int jo = 0; jo < 8; ++jo)
            #pragma unroll
            for (int r = 0; r < 4; ++r)
                o[jo][r] *= scl[r];
        #pragma unroll
        for (int jk = 0; jk < 4; ++jk)
            #pragma unroll
            for (int r = 0; r < 4; ++r) {
                int row = gl * 4 + r;
                Ps[w][(row * 64 + jk * 16 + lc) ^ ((row & 7) << 3)] = f2bf(s[jk][r]);
            }
        #pragma unroll
        for (int ks = 0; ks < 2; ++ks) {
            bf16x8 pa = *(const bf16x8*)&Ps[w][(lc * 64 + ks * 32 + gl * 8) ^ ((lc & 7) << 3)];
            #pragma unroll
            for (int jo = 0; jo < 8; ++jo) {
                bf16x8 bv_ = *(const bf16x8*)&vb[(size_t)(jo * 16 + lc) * T_ + kv0 + ks * 32 + gl * 8];
                o[jo] = __builtin_amdgcn_mfma_f32_16x16x32_bf16(pa, bv_, o[jo], 0, 0, 0);
            }
        }
    }
    float* ob = out + (size_t)bb * T_ * H_;
    #pragma unroll
    for (int jo = 0; jo < 8; ++jo)
        #pragma unroll
        for (int r = 0; r < 4; ++r)
            ob[(size_t)(q0 + w * 16 + gl * 4 + r) * H_ + jo * 16 + lc] = o[jo][r] / l_run[r];
}

extern "C" void kernel_launch(void* const* d_in, const int* in_sizes, int n_in,
                              void* d_out, int out_size, void* d_ws, size_t ws_size,
                              hipStream_t stream) {
    const float* x  = (const float*)d_in[0];
    const float* Wq = (const float*)d_in[1];
    const float* bq = (const float*)d_in[2];
    const float* Wk = (const float*)d_in[3];
    const float* bk = (const float*)d_in[4];
    const float* Wv = (const float*)d_in[5];
    const float* bv = (const float*)d_in[6];
    float* out = (float*)d_out;

    const size_t qkv = (size_t)B_ * T_ * H_;               // 2M elems
    unsigned short* qws = (unsigned short*)d_ws;
    unsigned short* kws = qws + qkv;
    unsigned short* vws = kws + qkv;                       // [B,H,T] transposed
    unsigned short* wtw = vws + qkv;                       // [3,H,C]
    const size_t base_bytes = (3 * qkv + (size_t)3 * H_ * C_) * 2;  // 13,369,344
    unsigned short* Opart = (unsigned short*)((char*)d_ws + base_bytes);  // 1120 x 8192 bf16
    float* lws = (float*)((char*)d_ws + base_bytes + (size_t)1120 * 8192 * 2);
    const size_t need = base_bytes + (size_t)1120 * 8192 * 2 + (size_t)1120 * 64 * 4;

    prep_w<<<dim3(192), 256, 0, stream>>>(Wq, Wk, Wv, wtw);
    proj_kernel<<<dim3(256, 3), 256, 0, stream>>>(x, wtw, bq, bk, bv, qws, kws, vws);
    if (ws_size >= need) {
        attn_split7<<<dim3(8, 144), 256, 0, stream>>>(qws, kws, vws, out, Opart, lws);
        combine_kernel<<<dim3(3584), 256, 0, stream>>>(Opart, lws, out);
    } else {
        attn_mono<<<dim3(64, 8), 128, 0, stream>>>(qws, kws, vws, out);
    }
}

// Round 10
// 74.243 us; speedup vs baseline: 2.0173x; 1.0790x over previous
//
#include <hip/hip_runtime.h>
#include <cstdint>
#include <cstddef>

typedef __bf16 bf16x8 __attribute__((ext_vector_type(8)));
typedef float f32x4 __attribute__((ext_vector_type(4)));

#define B_ 8
#define T_ 2048
#define C_ 1024
#define H_ 128

// C^-0.5 * log2(e): folded into Q at projection; softmax runs in exp2-space.
#define QSC 0.045084220027780106f

__device__ __forceinline__ unsigned short f2bf(float f) {
    __bf16 h = (__bf16)f;
    return *(unsigned short*)&h;
}
__device__ __forceinline__ float bf2f(unsigned short u) {
    union { unsigned int i; float f; } x; x.i = ((unsigned int)u) << 16;
    return x.f;
}

// async global->LDS, 16B per lane. LDS dest must be the wave-uniform base;
// HW adds lane*16. Global src is per-lane.
__device__ __forceinline__ void gload16(void* lds, const void* g) {
    __builtin_amdgcn_global_load_lds(
        (const __attribute__((address_space(1))) unsigned int*)g,
        (__attribute__((address_space(3))) unsigned int*)lds, 16, 0, 0);
}

// ---------------------------------------------------------------------------
// prep_w: WT[which][n][k] bf16  <-  W[k][n] f32.  Row index R = which*128+n.
// ---------------------------------------------------------------------------
__global__ __launch_bounds__(256) void prep_w(
    const float* __restrict__ Wq, const float* __restrict__ Wk,
    const float* __restrict__ Wv, unsigned short* __restrict__ wt)
{
    int gid = blockIdx.x * 256 + threadIdx.x;        // 49152 total
    int which = gid >> 14;
    int rem = gid & 16383;
    int n = rem >> 7;            // 0..127
    int kc = rem & 127;          // k-chunk of 8
    const float* W = which == 0 ? Wq : (which == 1 ? Wk : Wv);
    unsigned short tmp[8];
    #pragma unroll
    for (int i = 0; i < 8; ++i) tmp[i] = f2bf(W[(size_t)(kc * 8 + i) * H_ + n]);
    *(uint4*)&wt[((size_t)which * H_ + n) * C_ + kc * 8] = *(uint4*)tmp;
}

// ---------------------------------------------------------------------------
// proj_fused: q,k,v for one 64-row m-tile in ONE block (x read once).
// BM=64, BN=384 (q|k|v), BK=64. 512 threads = 8 waves as 4M x 2N:
// wave w: rows (w>>1)*16..+15, cols (w&1)*192..+191 (12 jn tiles).
// x staged f32 via gload16 (dbuf 32KB); W^T[384][64] bf16 (dbuf 96KB).
// LDS=128KB -> 1 block/CU, grid 256 = 1/CU. HBM-streaming bound on x.
// Epilogue: acc -> LDS (stride 392 for bank spread) -> coalesced stores;
// Q scaled by QSC, V stored transposed [B,H,T].
// ---------------------------------------------------------------------------
__global__ __launch_bounds__(512, 2) void proj_fused(
    const float* __restrict__ x, const unsigned short* __restrict__ wt,
    const float* __restrict__ bq, const float* __restrict__ bk,
    const float* __restrict__ bv,
    unsigned short* __restrict__ qo, unsigned short* __restrict__ ko,
    unsigned short* __restrict__ vo)
{
    __shared__ float xs[2][64 * 64];             // 32 KB, [m][k] f32, unit-XOR swz
    __shared__ unsigned short ws2[2][384 * 64];  // 96 KB, [R][k] bf16, chunk-XOR swz

    const int tid = threadIdx.x;
    const int w = tid >> 6, l = tid & 63, gl = l >> 4, lc = l & 15;
    const int rb = (w >> 1) * 16;    // row band
    const int cb = (w & 1) * 192;    // col half
    const int m0 = blockIdx.x * 64;

    f32x4 acc[12];
    #pragma unroll
    for (int jn = 0; jn < 12; ++jn) acc[jn] = f32x4{0.f, 0.f, 0.f, 0.f};

    auto stage = [&](int buf, int kc2) {
        const int kb = kc2 * 64;
        // W^T: 3072 16B units (384 rows x 8 chunks)
        #pragma unroll
        for (int ji = 0; ji < 6; ++ji) {
            int slot = ji * 512 + tid;
            int R = slot >> 3, cs = slot & 7;
            gload16(&ws2[buf][(ji * 512 + w * 64) * 8],
                    &wt[(size_t)R * C_ + kb + ((cs ^ (R & 7)) * 8)]);
        }
        // x: 1024 16B units (64 rows x 16 chunks of 4 f32)
        #pragma unroll
        for (int ji = 0; ji < 2; ++ji) {
            int slot = ji * 512 + tid;
            int r = slot >> 4, cs = slot & 15;
            gload16(&xs[buf][(ji * 512 + w * 64) * 4],
                    &x[(size_t)(m0 + r) * C_ + kb + ((cs ^ (r & 15)) * 4)]);
        }
    };

    stage(0, 0);
    __syncthreads();

    int cur = 0;
    for (int kc = 0; kc < 16; ++kc) {
        if (kc < 15) stage(cur ^ 1, kc + 1);
        #pragma unroll
        for (int ks = 0; ks < 2; ++ks) {
            // a-fragment: rows rb..rb+15, k = ks*32 + gl*8
            const int row = rb + lc;
            const int u0 = ks * 8 + gl * 2;
            f32x4 lo = *(const f32x4*)&xs[cur][(row * 16 + (u0 ^ (row & 15))) * 4];
            f32x4 hi = *(const f32x4*)&xs[cur][(row * 16 + ((u0 + 1) ^ (row & 15))) * 4];
            bf16x8 af;
            af[0] = (__bf16)lo[0]; af[1] = (__bf16)lo[1];
            af[2] = (__bf16)lo[2]; af[3] = (__bf16)lo[3];
            af[4] = (__bf16)hi[0]; af[5] = (__bf16)hi[1];
            af[6] = (__bf16)hi[2]; af[7] = (__bf16)hi[3];
            #pragma unroll
            for (int jn = 0; jn < 12; ++jn) {
                int R = cb + jn * 16 + lc;
                bf16x8 bfr = *(const bf16x8*)&ws2[cur][(R * 8 + ((ks * 4 + gl) ^ (R & 7))) * 8];
                acc[jn] = __builtin_amdgcn_mfma_f32_16x16x32_bf16(af, bfr, acc[jn], 0, 0, 0);
            }
        }
        __syncthreads();
        cur ^= 1;
    }

    // epilogue: acc -> eb (bf16, stride 392 for v-transpose bank spread)
    unsigned short* eb = (unsigned short*)&ws2[0][0];   // 64*392 = 50,176 B
    #pragma unroll
    for (int jn = 0; jn < 12; ++jn) {
        int n = cb + jn * 16 + lc;
        int wh = n >> 7, nl = n & 127;
        float bb = (wh == 0) ? bq[nl] : (wh == 1 ? bk[nl] : bv[nl]);
        float sc = (wh == 0) ? QSC : 1.0f;
        #pragma unroll
        for (int r = 0; r < 4; ++r) {
            int row = rb + gl * 4 + r;
            eb[row * 392 + n] = f2bf((acc[jn][r] + bb) * sc);
        }
    }
    __syncthreads();

    const int bi = m0 >> 11, t0 = m0 & (T_ - 1);
    #pragma unroll
    for (int i = 0; i < 2; ++i) {
        int c = i * 512 + tid;                 // 0..1023
        // q: [64 rows][128 cols] -> 16B chunks
        {
            int row = c >> 4, c16 = c & 15;
            *(uint4*)&qo[(size_t)(m0 + row) * H_ + c16 * 8] =
                *(const uint4*)&eb[row * 392 + c16 * 8];
            *(uint4*)&ko[(size_t)(m0 + row) * H_ + c16 * 8] =
                *(const uint4*)&eb[row * 392 + 128 + c16 * 8];
        }
        // v transposed: vT[n][t0+cc*8..+7] from eb[t][256+n]
        {
            int n = c >> 3, cc = c & 7;
            unsigned short tmp[8];
            #pragma unroll
            for (int ii = 0; ii < 8; ++ii)
                tmp[ii] = eb[(cc * 8 + ii) * 392 + 256 + n];
            *(uint4*)&vo[((size_t)(bi * H_ + n)) * T_ + t0 + cc * 8] = *(uint4*)tmp;
        }
    }
}

// pasc(qt) = number of jobs for q-tiles < qt (QBLK=64, chunk=256):
// nch(i) = ceil((i+1)/4); pasc = 2m(m+1) + j(m+1), m=qt>>2, j=qt&3.
__device__ __forceinline__ int pasc(int qt) {
    int m = qt >> 2, j = qt & 3;
    return 2 * m * (m + 1) + j * (m + 1);
}

// ---------------------------------------------------------------------------
// attn_split7: KV-split flash attention, 4 waves (QBLK=64) sharing K/V LDS.
// grid (8 batch=XCD pin, 144 jobs). KVBLK=32, chunk=256 keys.
// LDS = 16+16+8 = 40KB -> 4 blocks/CU = 16 waves/CU resident.
// No-max exp2 softmax; bf16 partials; plain-sum combine.
// ---------------------------------------------------------------------------
__global__ __launch_bounds__(256, 2) void attn_split7(
    const unsigned short* __restrict__ q,
    const unsigned short* __restrict__ k,
    const unsigned short* __restrict__ vT,
    float* __restrict__ out,
    unsigned short* __restrict__ Opart, float* __restrict__ lws)
{
    const int bb = blockIdx.x;                 // batch -> XCD pin
    const int jj = 143 - (int)blockIdx.y;      // longest jobs first
    int qt = 31;
    while (pasc(qt) > jj) --qt;
    const int c = jj - pasc(qt);
    const int nch = (qt >> 2) + 1;
    const int q0 = qt * 64;
    const int kstart = c * 256;
    const int kend = min(kstart + 256, q0 + 64);
    const int ntiles = (kend - kstart) >> 5;   // 1..8

    const unsigned short* qb = q  + (size_t)bb * T_ * H_;
    const unsigned short* kb = k  + (size_t)bb * T_ * H_;
    const unsigned short* vb = vT + (size_t)bb * H_ * T_;

    __shared__ unsigned short Ks[2][32 * 128];   // [key][d], chunk-XOR swizzled
    __shared__ unsigned short Vs[2][128 * 32];   // [d][key], chunk-XOR swizzled
    __shared__ unsigned short Ps[4][16 * 64];    // per-wave P

    const int tid = threadIdx.x;
    const int w = tid >> 6, l = tid & 63, gl = l >> 4, lc = l & 15;
    const int rowbase = q0 + w * 16;             // this wave's first q row

    bf16x8 aq[4];
    #pragma unroll
    for (int ds = 0; ds < 4; ++ds)
        aq[ds] = *(const bf16x8*)&qb[(size_t)(rowbase + lc) * H_ + ds * 32 + gl * 8];

    f32x4 o[8];
    #pragma unroll
    for (int jo = 0; jo < 8; ++jo) o[jo] = f32x4{0.f, 0.f, 0.f, 0.f};
    float l_acc[4];
    #pragma unroll
    for (int r = 0; r < 4; ++r) l_acc[r] = 0.f;

    auto stageK = [&](int buf, int t) {
        const int kv0 = kstart + t * 32;
        #pragma unroll
        for (int ji = 0; ji < 2; ++ji) {
            int slot = (w * 2 + ji) * 64 + l;
            int r = slot >> 4, cs = slot & 15;
            gload16(&Ks[buf][((w * 2 + ji) * 64) * 8],
                    &kb[(size_t)(kv0 + r) * H_ + ((cs ^ (r & 7)) * 8)]);
        }
    };
    auto stageV = [&](int buf, int t) {
        const int kv0 = kstart + t * 32;
        #pragma unroll
        for (int ji = 0; ji < 2; ++ji) {
            int slot = (w * 2 + ji) * 64 + l;
            int r = slot >> 2, cs = slot & 3;
            gload16(&Vs[buf][((w * 2 + ji) * 64) * 8],
                    &vb[(size_t)r * T_ + kv0 + ((cs ^ (r & 3)) * 8)]);
        }
    };

    stageK(0, 0);
    stageV(0, 0);
    __syncthreads();

    int cur = 0;
    for (int t = 0; t < ntiles; ++t) {
        if (t + 1 < ntiles) { stageK(cur ^ 1, t + 1); stageV(cur ^ 1, t + 1); }
        const int kv0 = kstart + t * 32;
        const bool active = kv0 < rowbase + 16;
        if (active) {
            f32x4 s[2];
            #pragma unroll
            for (int jk = 0; jk < 2; ++jk) s[jk] = f32x4{0.f, 0.f, 0.f, 0.f};
            #pragma unroll
            for (int ds = 0; ds < 4; ++ds) {
                #pragma unroll
                for (int jk = 0; jk < 2; ++jk) {
                    int row = jk * 16 + lc;
                    bf16x8 kf = *(const bf16x8*)&Ks[cur][(row * 16 + ((ds * 4 + gl) ^ (row & 7))) * 8];
                    s[jk] = __builtin_amdgcn_mfma_f32_16x16x32_bf16(aq[ds], kf, s[jk], 0, 0, 0);
                }
            }
            if (kv0 + 31 > rowbase) {
                #pragma unroll
                for (int jk = 0; jk < 2; ++jk)
                    #pragma unroll
                    for (int r = 0; r < 4; ++r)
                        if (kv0 + jk * 16 + lc > rowbase + gl * 4 + r) s[jk][r] = -1e30f;
            }
            #pragma unroll
            for (int jk = 0; jk < 2; ++jk)
                #pragma unroll
                for (int r = 0; r < 4; ++r) {
                    float p = exp2f(fminf(s[jk][r], 80.f));
                    s[jk][r] = p;
                    l_acc[r] += p;
                }
            #pragma unroll
            for (int jk = 0; jk < 2; ++jk)
                #pragma unroll
                for (int r = 0; r < 4; ++r) {
                    int row = gl * 4 + r;
                    Ps[w][(row * 64 + jk * 16 + lc) ^ ((row & 7) << 3)] = f2bf(s[jk][r]);
                }
            {
                bf16x8 pa = *(const bf16x8*)&Ps[w][(lc * 64 + gl * 8) ^ ((lc & 7) << 3)];
                #pragma unroll
                for (int jo = 0; jo < 8; ++jo) {
                    int d = jo * 16 + lc;
                    bf16x8 vf = *(const bf16x8*)&Vs[cur][(d * 4 + (gl ^ (d & 3))) * 8];
                    o[jo] = __builtin_amdgcn_mfma_f32_16x16x32_bf16(pa, vf, o[jo], 0, 0, 0);
                }
            }
        }
        __syncthreads();
        cur ^= 1;
    }

    #pragma unroll
    for (int off = 1; off < 16; off <<= 1)
        #pragma unroll
        for (int r = 0; r < 4; ++r)
            l_acc[r] += __shfl_xor(l_acc[r], off, 64);

    if (nch == 1) {
        float* ob = out + (size_t)bb * T_ * H_;
        float inv[4];
        #pragma unroll
        for (int r = 0; r < 4; ++r) inv[r] = 1.0f / l_acc[r];
        #pragma unroll
        for (int jo = 0; jo < 8; ++jo)
            #pragma unroll
            for (int r = 0; r < 4; ++r)
                ob[(size_t)(rowbase + gl * 4 + r) * H_ + jo * 16 + lc] = o[jo][r] * inv[r];
    } else {
        const int slot = bb * 140 + (pasc(qt) - 4 + c);
        unsigned short* op = Opart + (size_t)slot * 8192;
        #pragma unroll
        for (int jo = 0; jo < 8; ++jo)
            #pragma unroll
            for (int r = 0; r < 4; ++r)
                op[(w * 16 + gl * 4 + r) * 128 + jo * 16 + lc] = f2bf(o[jo][r]);
        if (lc == 0) {
            #pragma unroll
            for (int r = 0; r < 4; ++r)
                lws[slot * 64 + w * 16 + gl * 4 + r] = l_acc[r];
        }
    }
}

// ---------------------------------------------------------------------------
// combine: out[t] = sum_c O_c[t] / sum_c l_c[t] for t >= 256 (bf16 partials).
// ---------------------------------------------------------------------------
__global__ __launch_bounds__(256) void combine_kernel(
    const unsigned short* __restrict__ Opart, const float* __restrict__ lws,
    float* __restrict__ out)
{
    const int rowid = blockIdx.x * 4 + (threadIdx.x >> 6);   // 0..14335
    const int lane = threadIdx.x & 63;
    const int bb = rowid / 1792;
    const int t = 256 + (rowid - bb * 1792);                 // 256..2047
    const int qt = t >> 6;                                    // 4..31
    const int m = qt >> 2;
    const int nch = m + 1;
    const int p0 = 2 * m * (m + 1) + (qt & 3) * (m + 1);     // pasc(qt)
    const int base = bb * 140 + (p0 - 4);
    const int r64 = t & 63;

    float L = 0.f, a0 = 0.f, a1 = 0.f;
    #pragma unroll
    for (int c2 = 0; c2 < 8; ++c2)
        if (c2 < nch) {
            L += lws[(base + c2) * 64 + r64];
            ushort2 uv = *(const ushort2*)&Opart[(size_t)(base + c2) * 8192 + r64 * 128 + lane * 2];
            a0 += bf2f(uv.x); a1 += bf2f(uv.y);
        }
    const float invL = 1.0f / L;
    *(float2*)&out[((size_t)bb * T_ + t) * H_ + lane * 2] = make_float2(a0 * invL, a1 * invL);
}

// ---------------------------------------------------------------------------
// Fallback monolithic attention (only if ws too small). Max-tracking version.
// ---------------------------------------------------------------------------
__global__ __launch_bounds__(128) void attn_mono(
    const unsigned short* __restrict__ q,
    const unsigned short* __restrict__ k,
    const unsigned short* __restrict__ vT,
    float* __restrict__ out)
{
    const int qt = (gridDim.x - 1) - blockIdx.x;
    const int bb = blockIdx.y;
    const int q0 = qt * 32;
    const unsigned short* qb = q  + (size_t)bb * T_ * H_;
    const unsigned short* kb = k  + (size_t)bb * T_ * H_;
    const unsigned short* vb = vT + (size_t)bb * H_ * T_;

    __shared__ unsigned short Ps[2][16 * 64];

    const int tid = threadIdx.x;
    const int w = tid >> 6, l = tid & 63, gl = l >> 4, lc = l & 15;

    bf16x8 aq[4];
    #pragma unroll
    for (int ds = 0; ds < 4; ++ds)
        aq[ds] = *(const bf16x8*)&qb[(size_t)(q0 + w * 16 + lc) * H_ + ds * 32 + gl * 8];

    f32x4 o[8];
    #pragma unroll
    for (int jo = 0; jo < 8; ++jo) o[jo] = f32x4{0.f, 0.f, 0.f, 0.f};
    float m_run[4], l_run[4];
    #pragma unroll
    for (int r = 0; r < 4; ++r) { m_run[r] = -INFINITY; l_run[r] = 0.f; }

    const int nt = (q0 >> 6) + 1;
    for (int t = 0; t < nt; ++t) {
        const int kv0 = t * 64;
        f32x4 s[4];
        #pragma unroll
        for (int jk = 0; jk < 4; ++jk) s[jk] = f32x4{0.f, 0.f, 0.f, 0.f};
        #pragma unroll
        for (int ds = 0; ds < 4; ++ds)
            #pragma unroll
            for (int jk = 0; jk < 4; ++jk) {
                bf16x8 bf = *(const bf16x8*)&kb[(size_t)(kv0 + jk * 16 + lc) * H_ + ds * 32 + gl * 8];
                s[jk] = __builtin_amdgcn_mfma_f32_16x16x32_bf16(aq[ds], bf, s[jk], 0, 0, 0);
            }
        if (kv0 + 63 > q0) {
            const int rowg = q0 + w * 16 + gl * 4;
            #pragma unroll
            for (int jk = 0; jk < 4; ++jk)
                #pragma unroll
                for (int r = 0; r < 4; ++r)
                    if (kv0 + jk * 16 + lc > rowg + r) s[jk][r] = -1e30f;
        }
        float pm[4];
        #pragma unroll
        for (int r = 0; r < 4; ++r)
            pm[r] = fmaxf(fmaxf(s[0][r], s[1][r]), fmaxf(s[2][r], s[3][r]));
        #pragma unroll
        for (int off = 1; off < 16; off <<= 1)
            #pragma unroll
            for (int r = 0; r < 4; ++r)
                pm[r] = fmaxf(pm[r], __shfl_xor(pm[r], off, 64));
        float scl[4], rs[4];
        #pragma unroll
        for (int r = 0; r < 4; ++r) {
            float mn = fmaxf(m_run[r], pm[r]);
            scl[r] = exp2f(m_run[r] - mn);
            m_run[r] = mn;
            rs[r] = 0.f;
        }
        #pragma unroll
        for (int jk = 0; jk < 4; ++jk)
            #pragma unroll
            for (int r = 0; r < 4; ++r) {
                float p = exp2f(s[jk][r] - m_run[r]);
                s[jk][r] = p;
                rs[r] += p;
            }
        #pragma unroll
        for (int off = 1; off < 16; off <<= 1)
            #pragma unroll
            for (int r = 0; r < 4; ++r)
                rs[r] += __shfl_xor(rs[r], off, 64);
        #pragma unroll
        for (int r = 0; r < 4; ++r)
            l_run[r] = l_run[r] * scl[r] + rs[r];
        #pragma unroll
        for (int jo = 0; jo < 8; ++jo)
            #pragma unroll
            for (int r = 0; r < 4; ++r)
                o[jo][r] *= scl[r];
        #pragma unroll
        for (int jk = 0; jk < 4; ++jk)
            #pragma unroll
            for (int r = 0; r < 4; ++r) {
                int row = gl * 4 + r;
                Ps[w][(row * 64 + jk * 16 + lc) ^ ((row & 7) << 3)] = f2bf(s[jk][r]);
            }
        #pragma unroll
        for (int ks = 0; ks < 2; ++ks) {
            bf16x8 pa = *(const bf16x8*)&Ps[w][(lc * 64 + ks * 32 + gl * 8) ^ ((lc & 7) << 3)];
            #pragma unroll
            for (int jo = 0; jo < 8; ++jo) {
                bf16x8 bv_ = *(const bf16x8*)&vb[(size_t)(jo * 16 + lc) * T_ + kv0 + ks * 32 + gl * 8];
                o[jo] = __builtin_amdgcn_mfma_f32_16x16x32_bf16(pa, bv_, o[jo], 0, 0, 0);
            }
        }
    }
    float* ob = out + (size_t)bb * T_ * H_;
    #pragma unroll
    for (int jo = 0; jo < 8; ++jo)
        #pragma unroll
        for (int r = 0; r < 4; ++r)
            ob[(size_t)(q0 + w * 16 + gl * 4 + r) * H_ + jo * 16 + lc] = o[jo][r] / l_run[r];
}

extern "C" void kernel_launch(void* const* d_in, const int* in_sizes, int n_in,
                              void* d_out, int out_size, void* d_ws, size_t ws_size,
                              hipStream_t stream) {
    const float* x  = (const float*)d_in[0];
    const float* Wq = (const float*)d_in[1];
    const float* bq = (const float*)d_in[2];
    const float* Wk = (const float*)d_in[3];
    const float* bk = (const float*)d_in[4];
    const float* Wv = (const float*)d_in[5];
    const float* bv = (const float*)d_in[6];
    float* out = (float*)d_out;

    const size_t qkv = (size_t)B_ * T_ * H_;               // 2M elems
    unsigned short* qws = (unsigned short*)d_ws;
    unsigned short* kws = qws + qkv;
    unsigned short* vws = kws + qkv;                       // [B,H,T] transposed
    unsigned short* wtw = vws + qkv;                       // [3,H,C]
    const size_t base_bytes = (3 * qkv + (size_t)3 * H_ * C_) * 2;  // 13,369,344
    unsigned short* Opart = (unsigned short*)((char*)d_ws + base_bytes);  // 1120 x 8192 bf16
    float* lws = (float*)((char*)d_ws + base_bytes + (size_t)1120 * 8192 * 2);
    const size_t need = base_bytes + (size_t)1120 * 8192 * 2 + (size_t)1120 * 64 * 4;

    prep_w<<<dim3(192), 256, 0, stream>>>(Wq, Wk, Wv, wtw);
    proj_fused<<<dim3(256), 512, 0, stream>>>(x, wtw, bq, bk, bv, qws, kws, vws);
    if (ws_size >= need) {
        attn_split7<<<dim3(8, 144), 256, 0, stream>>>(qws, kws, vws, out, Opart, lws);
        combine_kernel<<<dim3(3584), 256, 0, stream>>>(Opart, lws, out);
    } else {
        attn_mono<<<dim3(64, 8), 128, 0, stream>>>(qws, kws, vws, out);
    }
}